// Round 4
// baseline (760.822 us; speedup 1.0000x reference)
//
#include <hip/hip_runtime.h>
#include <hip/hip_bf16.h>

// Problem constants
#define B_   4
#define C_   256
#define N_   3136
#define QT_  196     // N/16 q-tiles per batch
#define NKV_ 98      // N/32 kv tiles

typedef __attribute__((ext_vector_type(8))) short bf16x8;
typedef __attribute__((ext_vector_type(4))) float f32x4;

#define LOG2E  1.4426950408889634f
#define SCALE2 (LOG2E / 16.0f)     // (1/sqrt(C)) * log2(e)

__device__ __forceinline__ unsigned short bfbits(float f) {
  __hip_bfloat16 h = __float2bfloat16(f);
  return *(unsigned short*)&h;
}

// ---- async global->LDS 16B helper (dest must be linear: base + lane*16) ----
__device__ __forceinline__ void gld16(const void* g, void* l) {
  __builtin_amdgcn_global_load_lds(
      (const __attribute__((address_space(1))) unsigned int*)g,
      (__attribute__((address_space(3))) unsigned int*)l, 16, 0, 0);
}

// ---- [b][c][n] f32  ->  [b][n][c] bf16 tokens ----
__global__ __launch_bounds__(256) void transpose_tok_kernel(
    const float* __restrict__ src, __hip_bfloat16* __restrict__ dst) {
  __shared__ float tile[32][33];
  const int b  = blockIdx.z;
  const int n0 = blockIdx.x * 32;
  const int c0 = blockIdx.y * 32;
  const int tx = threadIdx.x & 31;
  const int ty = threadIdx.x >> 5;     // 0..7
  const float* s = src + (size_t)b * C_ * N_;
#pragma unroll
  for (int i = 0; i < 4; ++i) {
    int c = c0 + ty + i * 8;
    tile[ty + i * 8][tx] = s[(size_t)c * N_ + n0 + tx];
  }
  __syncthreads();
  __hip_bfloat16* d = dst + (size_t)b * N_ * C_;
#pragma unroll
  for (int i = 0; i < 4; ++i) {
    int n = n0 + ty + i * 8;
    d[(size_t)n * C_ + c0 + tx] = __float2bfloat16(tile[tx][ty + i * 8]);
  }
}

// ---- f32 -> bf16 flat convert (weights) ----
__global__ __launch_bounds__(256) void cvt_bf16_kernel(
    const float* __restrict__ src, __hip_bfloat16* __restrict__ dst, int n) {
  int i = blockIdx.x * 256 + threadIdx.x;
  if (i < n) dst[i] = __float2bfloat16(src[i]);
}

// ---- f32 -> bf16 mask convert, 8 elems/thread ----
__global__ __launch_bounds__(256) void cvt_mask_kernel(
    const float* __restrict__ src, __hip_bfloat16* __restrict__ dst, int n8) {
  int i = blockIdx.x * 256 + threadIdx.x;
  if (i >= n8) return;
  const float4* s = (const float4*)src;
  float4 a = s[2 * i], b = s[2 * i + 1];
  union { unsigned short u[8]; bf16x8 v; } p;
  p.u[0] = bfbits(a.x); p.u[1] = bfbits(a.y); p.u[2] = bfbits(a.z); p.u[3] = bfbits(a.w);
  p.u[4] = bfbits(b.x); p.u[5] = bfbits(b.y); p.u[6] = bfbits(b.z); p.u[7] = bfbits(b.w);
  *(bf16x8*)(dst + 8 * i) = p.v;
}

// ---- vT[b][c][n] = sum_k Wv[c][k] * f[b][n][k] + bv[c]   (written transposed) ----
__global__ __launch_bounds__(256) void v_linear_kernel(
    const __hip_bfloat16* __restrict__ fb,   // [B][N][C]
    const __hip_bfloat16* __restrict__ Wv,   // [C][C] bf16
    const float* __restrict__ bv,
    __hip_bfloat16* __restrict__ vT)         // [B][C][N]
{
  const int b    = blockIdx.z;
  const int cblk = blockIdx.y;
  const int nblk = blockIdx.x;
  const int wave = threadIdx.x >> 6;
  const int lane = threadIdx.x & 63;
  const int qt = lane & 15, g = lane >> 4;
  const int c0 = cblk * 64 + wave * 16;
  const int n0 = nblk * 64;
  const __hip_bfloat16* fbb = fb + (size_t)b * N_ * C_;
  f32x4 acc[4];
#pragma unroll
  for (int j = 0; j < 4; ++j) acc[j] = (f32x4){0.f, 0.f, 0.f, 0.f};
#pragma unroll
  for (int kk = 0; kk < 8; ++kk) {
    int ko = kk * 32 + g * 8;
    bf16x8 a = *(const bf16x8*)(Wv + (size_t)(c0 + qt) * C_ + ko);
#pragma unroll
    for (int j = 0; j < 4; ++j) {
      bf16x8 bb = *(const bf16x8*)(fbb + (size_t)(n0 + j * 16 + qt) * C_ + ko);
      acc[j] = __builtin_amdgcn_mfma_f32_16x16x32_bf16(a, bb, acc[j], 0, 0, 0);
    }
  }
  __hip_bfloat16* out = vT + (size_t)b * C_ * N_;
#pragma unroll
  for (int j = 0; j < 4; ++j)
#pragma unroll
    for (int r = 0; r < 4; ++r) {
      int c = c0 + 4 * g + r;
      int n = n0 + j * 16 + qt;
      out[(size_t)c * N_ + n] = __float2bfloat16(acc[j][r] + bv[c]);
    }
}

// ---- flash attention: 4 waves x 2 q-tiles, dbuf K/V, counted vmcnt ----
__global__ __launch_bounds__(256, 2) void attn_kernel(
    const __hip_bfloat16* __restrict__ qb,   // [B][N][C]
    const __hip_bfloat16* __restrict__ kb,   // [B][N][C]
    const __hip_bfloat16* __restrict__ vT,   // [B][C][N]
    const __hip_bfloat16* __restrict__ mb,   // [N][N] bf16
    __hip_bfloat16* __restrict__ pOt,        // [B][196][4][col*16+row] bf16
    float* __restrict__ pML)                 // [B][196][4][2][16]
{
  __shared__ __hip_bfloat16 Kl[2][32 * 256];   // 2 x 16KB
  __shared__ __hip_bfloat16 Vl[2][256 * 32];   // 2 x 16KB
  __shared__ __hip_bfloat16 Pl[4][2][512];     // 8KB

  const int bid   = blockIdx.x;       // 0..399
  const int grp   = bid & 15;         // (b,chunk): same grp -> same XCD class
  const int qblk  = bid >> 4;         // 0..24
  const int b     = grp >> 2;
  const int chunk = grp & 3;
  const int wave  = threadIdx.x >> 6;
  const int lane  = threadIdx.x & 63;
  const int qt = lane & 15, g = lane >> 4;
  const int qtile0 = qblk * 8 + wave * 2;
  const int qtile1 = qtile0 + 1;
  const bool val0 = qtile0 < QT_;
  const bool val1 = qtile1 < QT_;
  const int q0A = (val0 ? qtile0 : QT_ - 1) * 16;
  const int q0B = (val1 ? qtile1 : QT_ - 1) * 16;
  const int t0 = (chunk * NKV_) >> 2;
  const int t1 = ((chunk + 1) * NKV_) >> 2;
  const int nt = t1 - t0;

  const __hip_bfloat16* qbb = qb + (size_t)b * N_ * C_;
  const __hip_bfloat16* kbb = kb + (size_t)b * N_ * C_;
  const __hip_bfloat16* vbb = vT + (size_t)b * C_ * N_;

  bf16x8 qa[2][8];
#pragma unroll
  for (int kk = 0; kk < 8; ++kk) {
    qa[0][kk] = *(const bf16x8*)(qbb + (size_t)(q0A + qt) * C_ + kk * 32 + g * 8);
    qa[1][kk] = *(const bf16x8*)(qbb + (size_t)(q0B + qt) * C_ + kk * 32 + g * 8);
  }

  f32x4 o[2][16];
#pragma unroll
  for (int j = 0; j < 2; ++j)
#pragma unroll
    for (int i = 0; i < 16; ++i) o[j][i] = (f32x4){0.f, 0.f, 0.f, 0.f};
  float mrow[2][4] = {{-1e30f,-1e30f,-1e30f,-1e30f},{-1e30f,-1e30f,-1e30f,-1e30f}};
  float lrow[2][4] = {{0.f,0.f,0.f,0.f},{0.f,0.f,0.f,0.f}};

  char* Pw0 = (char*)&Pl[wave][0][0];
  char* Pw1 = (char*)&Pl[wave][1][0];
  const int tid = threadIdx.x;

  // stage K/V tile t into buffer buf: 8 gld16 per thread (256 threads)
  auto STAGE = [&](int buf, int t) {
    const int k0 = t * 32;
#pragma unroll
    for (int i = 0; i < 4; ++i) {     // K: 32 rows x 512B; slot s holds key perm(s)
      int off  = (tid + i * 256) * 16;
      int slot = off >> 9;
      int key  = (slot < 16) ? (2 * slot) : (2 * slot - 31);
      int cb   = (off & 511) ^ ((slot & 7) << 4);
      gld16((const char*)(kbb + (size_t)(k0 + key) * C_) + cb, (char*)&Kl[buf][0] + off);
    }
#pragma unroll
    for (int i = 0; i < 4; ++i) {     // V^T: 256 rows x 64B, natural key order
      int off = (tid + i * 256) * 16;
      int row = off >> 6;
      int cb  = (off & 63) ^ (((row >> 1) & 3) << 4);
      gld16((const char*)(vbb + (size_t)row * N_ + k0) + cb, (char*)&Vl[buf][0] + off);
    }
  };
  // prefetch mask for tile t into 8 regs (2 bf16 each)
  auto MLOAD = [&](int t, unsigned int (&mm)[2][4]) {
    const int k0 = t * 32;
#pragma unroll
    for (int r = 0; r < 4; ++r) {
      mm[0][r] = *(const unsigned int*)(mb + (size_t)(q0A + 4 * g + r) * N_ + k0 + 2 * qt);
      mm[1][r] = *(const unsigned int*)(mb + (size_t)(q0B + 4 * g + r) * N_ + k0 + 2 * qt);
    }
  };

  // softmax for one q-tile: s0/s1 = raw scores, mc = mask regs; updates state, writes P
  auto SOFTMAX = [&](f32x4& s0, f32x4& s1, unsigned int (&mc)[4],
                     float (&mr)[4], float (&lr)[4], f32x4 (&oo)[16], char* Pw) {
    float v0[4], v1[4];
    unsigned long long bal = 0ull;
#pragma unroll
    for (int r = 0; r < 4; ++r) {
      float mf0 = __uint_as_float(mc[r] << 16);
      float mf1 = __uint_as_float(mc[r] & 0xffff0000u);
      v0[r] = fmaf(mf0, LOG2E, s0[r] * SCALE2);
      v1[r] = fmaf(mf1, LOG2E, s1[r] * SCALE2);
      float vm = fmaxf(v0[r], v1[r]);
      bal |= __ballot(vm > mr[r] + 8.f);
    }
    if (bal) {                   // rare: row max grew -> rescale
      float frv[4];
#pragma unroll
      for (int r = 0; r < 4; ++r) {
        float mx = fmaxf(v0[r], v1[r]);
#pragma unroll
        for (int d = 1; d < 16; d <<= 1) mx = fmaxf(mx, __shfl_xor(mx, d));
        float mn = fmaxf(mr[r], mx);
        frv[r] = exp2f(mr[r] - mn);
        mr[r] = mn;
        lr[r] *= frv[r];
      }
#pragma unroll
      for (int ct = 0; ct < 16; ++ct) {
        oo[ct][0] *= frv[0]; oo[ct][1] *= frv[1];
        oo[ct][2] *= frv[2]; oo[ct][3] *= frv[3];
      }
    }
#pragma unroll
    for (int r = 0; r < 4; ++r) {
      float p0 = exp2f(v0[r] - mr[r]);
      float p1 = exp2f(v1[r] - mr[r]);
      lr[r] += p0 + p1;
      unsigned int pk = (unsigned int)bfbits(p0) | ((unsigned int)bfbits(p1) << 16);
      int r4 = 4 * g + r;
      *(unsigned int*)(Pw + r4 * 64 + ((qt * 4) ^ (((r4 >> 1) & 3) << 4))) = pk;
    }
  };

  auto BODY = [&](int tti, int buf, unsigned int (&mcur)[2][4], unsigned int (&mnext)[2][4]) {
    if (tti + 1 < nt) {
      MLOAD(t0 + tti + 1, mnext);
      STAGE(buf ^ 1, t0 + tti + 1);
      asm volatile("s_waitcnt vmcnt(16)" ::: "memory");  // cur tile done; 16 new in flight
    } else {
      asm volatile("s_waitcnt vmcnt(0)" ::: "memory");
    }
    __builtin_amdgcn_s_barrier();

    // ---- S = Q @ K^T for both q-tiles (K-frags shared) ----
    f32x4 sA0 = (f32x4){0.f,0.f,0.f,0.f}, sA1 = (f32x4){0.f,0.f,0.f,0.f};
    f32x4 sB0 = (f32x4){0.f,0.f,0.f,0.f}, sB1 = (f32x4){0.f,0.f,0.f,0.f};
    const char* Kb = (const char*)&Kl[buf][0];
    __builtin_amdgcn_s_setprio(1);
#pragma unroll
    for (int kk = 0; kk < 8; ++kk) {
      int cb = (kk * 64 + g * 16) ^ ((qt & 7) << 4);
      bf16x8 kf0 = *(const bf16x8*)(Kb + qt * 512 + cb);
      bf16x8 kf1 = *(const bf16x8*)(Kb + (16 + qt) * 512 + cb);
      sA0 = __builtin_amdgcn_mfma_f32_16x16x32_bf16(qa[0][kk], kf0, sA0, 0, 0, 0);
      sB0 = __builtin_amdgcn_mfma_f32_16x16x32_bf16(qa[1][kk], kf0, sB0, 0, 0, 0);
      sA1 = __builtin_amdgcn_mfma_f32_16x16x32_bf16(qa[0][kk], kf1, sA1, 0, 0, 0);
      sB1 = __builtin_amdgcn_mfma_f32_16x16x32_bf16(qa[1][kk], kf1, sB1, 0, 0, 0);
    }
    __builtin_amdgcn_s_setprio(0);

    SOFTMAX(sA0, sA1, mcur[0], mrow[0], lrow[0], o[0], Pw0);
    SOFTMAX(sB0, sB1, mcur[1], mrow[1], lrow[1], o[1], Pw1);

    bf16x8 paA = *(const bf16x8*)(Pw0 + qt * 64 + ((g * 16) ^ (((qt >> 1) & 3) << 4)));
    bf16x8 paB = *(const bf16x8*)(Pw1 + qt * 64 + ((g * 16) ^ (((qt >> 1) & 3) << 4)));

    // ---- O += P @ V (V-frags shared) ----
    const char* Vb = (const char*)&Vl[buf][0];
    __builtin_amdgcn_s_setprio(1);
#pragma unroll
    for (int ct = 0; ct < 16; ++ct) {
      int row = ct * 16 + qt;
      int cb  = (g * 16) ^ (((qt >> 1) & 3) << 4);
      bf16x8 vf = *(const bf16x8*)(Vb + row * 64 + cb);
      o[0][ct] = __builtin_amdgcn_mfma_f32_16x16x32_bf16(paA, vf, o[0][ct], 0, 0, 0);
      o[1][ct] = __builtin_amdgcn_mfma_f32_16x16x32_bf16(paB, vf, o[1][ct], 0, 0, 0);
    }
    __builtin_amdgcn_s_setprio(0);
    __builtin_amdgcn_s_barrier();   // all waves done with buf before it is restaged
  };

  unsigned int mmA[2][4], mmB[2][4];
  STAGE(0, t0);
  MLOAD(t0, mmA);
  for (int tt = 0; tt < nt; tt += 2) {
    BODY(tt, 0, mmA, mmB);
    if (tt + 1 < nt) BODY(tt + 1, 1, mmB, mmA);
  }

  // final cross-lane reduce of deferred l partials + stores
#pragma unroll
  for (int j = 0; j < 2; ++j) {
    const bool vj = j ? val1 : val0;
    if (!vj) continue;
    const int qtile = j ? qtile1 : qtile0;
#pragma unroll
    for (int r = 0; r < 4; ++r) {
      float s = lrow[j][r];
#pragma unroll
      for (int d = 1; d < 16; d <<= 1) s += __shfl_xor(s, d);
      lrow[j][r] = s;
    }
    __hip_bfloat16* po = pOt + (((size_t)b * QT_ + qtile) * 4 + chunk) * 4096;
#pragma unroll
    for (int ct = 0; ct < 16; ++ct) {
      unsigned int lo = (unsigned int)bfbits(o[j][ct][0]) | ((unsigned int)bfbits(o[j][ct][1]) << 16);
      unsigned int hi = (unsigned int)bfbits(o[j][ct][2]) | ((unsigned int)bfbits(o[j][ct][3]) << 16);
      uint2 pk = make_uint2(lo, hi);
      *(uint2*)((char*)po + (ct * 16 + qt) * 32 + 8 * g) = pk;   // 8B coalesced
    }
    if (qt == 0) {
      float* pml = pML + (((size_t)b * QT_ + qtile) * 4 + chunk) * 32;
#pragma unroll
      for (int r = 0; r < 4; ++r) {
        pml[4 * g + r]      = mrow[j][r];
        pml[16 + 4 * g + r] = lrow[j][r];
      }
    }
  }
}

// ---- combine 4 KV-chunk partials; refined = O/l + f  -> bf16 [b][n][c] ----
// thread c (0..255) owns channel c; reads 16 contiguous rows per chunk
__global__ __launch_bounds__(256) void combine_kernel(
    const __hip_bfloat16* __restrict__ pOt, const float* __restrict__ pML,
    const __hip_bfloat16* __restrict__ fb,
    __hip_bfloat16* __restrict__ ref)
{
  __shared__ float sml[128];
  const int b = blockIdx.y;
  const int qtile = blockIdx.x;
  const int c = threadIdx.x;
  const float* pml = pML + ((size_t)b * QT_ + qtile) * 4 * 32;
  if (c < 128) sml[c] = pml[c];
  __syncthreads();

  float wgt[4][16];
#pragma unroll
  for (int row = 0; row < 16; ++row) {
    float m0 = sml[row], m1 = sml[32 + row], m2 = sml[64 + row], m3 = sml[96 + row];
    float M = fmaxf(fmaxf(m0, m1), fmaxf(m2, m3));
    float w0 = exp2f(m0 - M), w1 = exp2f(m1 - M), w2 = exp2f(m2 - M), w3 = exp2f(m3 - M);
    float L = w0 * sml[16 + row] + w1 * sml[48 + row] + w2 * sml[80 + row] + w3 * sml[112 + row];
    float iL = 1.f / L;
    wgt[0][row] = w0 * iL; wgt[1][row] = w1 * iL; wgt[2][row] = w2 * iL; wgt[3][row] = w3 * iL;
  }

  float acc[16];
#pragma unroll
  for (int row = 0; row < 16; ++row) acc[row] = 0.f;
#pragma unroll
  for (int ch = 0; ch < 4; ++ch) {
    const __hip_bfloat16* p = pOt + (((size_t)b * QT_ + qtile) * 4 + ch) * 4096 + c * 16;
    bf16x8 x0 = *(const bf16x8*)p;
    bf16x8 x1 = *(const bf16x8*)(p + 8);
#pragma unroll
    for (int row = 0; row < 8; ++row) {
      acc[row]     += wgt[ch][row]     * __uint_as_float((unsigned int)(unsigned short)x0[row] << 16);
      acc[row + 8] += wgt[ch][row + 8] * __uint_as_float((unsigned int)(unsigned short)x1[row] << 16);
    }
  }

  const __hip_bfloat16* f = fb + ((size_t)b * N_ + qtile * 16) * C_ + c;
  __hip_bfloat16* rf = ref + ((size_t)b * N_ + qtile * 16) * C_ + c;
#pragma unroll
  for (int row = 0; row < 16; ++row)
    rf[row * C_] = __float2bfloat16(acc[row] + __bfloat162float(f[row * C_]));
}

// ---- out[c][n] = Wl[:, :256] @ refined^T + Wl[:, 256:] @ f^T + bl ----
__global__ __launch_bounds__(256) void out_linear_kernel(
    const __hip_bfloat16* __restrict__ refb,
    const __hip_bfloat16* __restrict__ fb,
    const __hip_bfloat16* __restrict__ Wl,   // [256][512]
    const float* __restrict__ bl,
    float* __restrict__ out)
{
  const int b    = blockIdx.z;
  const int cblk = blockIdx.y;
  const int nblk = blockIdx.x;
  const int wave = threadIdx.x >> 6;
  const int lane = threadIdx.x & 63;
  const int qt = lane & 15, g = lane >> 4;
  const int c0 = cblk * 64 + wave * 16;
  const int n0 = nblk * 64;
  const __hip_bfloat16* rb  = refb + (size_t)b * N_ * C_;
  const __hip_bfloat16* fbb = fb  + (size_t)b * N_ * C_;
  f32x4 acc[4];
#pragma unroll
  for (int j = 0; j < 4; ++j) acc[j] = (f32x4){0.f, 0.f, 0.f, 0.f};
#pragma unroll
  for (int kk = 0; kk < 8; ++kk) {
    int ko = kk * 32 + g * 8;
    bf16x8 a = *(const bf16x8*)(Wl + (size_t)(c0 + qt) * 512 + ko);
#pragma unroll
    for (int j = 0; j < 4; ++j) {
      bf16x8 bb = *(const bf16x8*)(rb + (size_t)(n0 + j * 16 + qt) * C_ + ko);
      acc[j] = __builtin_amdgcn_mfma_f32_16x16x32_bf16(a, bb, acc[j], 0, 0, 0);
    }
  }
#pragma unroll
  for (int kk = 0; kk < 8; ++kk) {
    int ko = kk * 32 + g * 8;
    bf16x8 a = *(const bf16x8*)(Wl + (size_t)(c0 + qt) * 512 + 256 + ko);
#pragma unroll
    for (int j = 0; j < 4; ++j) {
      bf16x8 bb = *(const bf16x8*)(fbb + (size_t)(n0 + j * 16 + qt) * C_ + ko);
      acc[j] = __builtin_amdgcn_mfma_f32_16x16x32_bf16(a, bb, acc[j], 0, 0, 0);
    }
  }
  float* ob = out + (size_t)b * 4 * C_ * N_;
#pragma unroll
  for (int j = 0; j < 4; ++j)
#pragma unroll
    for (int r = 0; r < 4; ++r) {
      int c = c0 + 4 * g + r;
      int n = n0 + j * 16 + qt;
      ob[(size_t)c * N_ + n] = acc[j][r] + bl[c];
    }
}

extern "C" void kernel_launch(void* const* d_in, const int* in_sizes, int n_in,
                              void* d_out, int out_size, void* d_ws, size_t ws_size,
                              hipStream_t stream) {
  (void)in_sizes; (void)n_in; (void)out_size; (void)ws_size;
  const float* feat0 = (const float*)d_in[0];
  const float* feat1 = (const float*)d_in[1];
  const float* feat2 = (const float*)d_in[2];
  const float* feat3 = (const float*)d_in[3];
  const float* mask  = (const float*)d_in[7];
  const float* Wv    = (const float*)d_in[8];
  const float* bv    = (const float*)d_in[9];
  const float* Wl    = (const float*)d_in[10];
  const float* bl    = (const float*)d_in[11];
  float* out = (float*)d_out;

  const size_t TOKB = (size_t)B_ * N_ * C_ * 2;  // 6,422,528
  char* w = (char*)d_ws;
  __hip_bfloat16* q0   = (__hip_bfloat16*)(w);
  __hip_bfloat16* f1   = (__hip_bfloat16*)(w + TOKB);
  __hip_bfloat16* f2   = (__hip_bfloat16*)(w + 2 * TOKB);
  __hip_bfloat16* f3   = (__hip_bfloat16*)(w + 3 * TOKB);
  __hip_bfloat16* vT   = (__hip_bfloat16*)(w + 4 * TOKB);
  __hip_bfloat16* refA = (__hip_bfloat16*)(w + 5 * TOKB);
  __hip_bfloat16* refB = (__hip_bfloat16*)(w + 6 * TOKB);
  char* w2 = w + 7 * TOKB;
  __hip_bfloat16* Wv_bf = (__hip_bfloat16*)(w2);
  __hip_bfloat16* Wl_bf = (__hip_bfloat16*)(w2 + 131072);
  __hip_bfloat16* maskb = (__hip_bfloat16*)(w2 + 393216);
  __hip_bfloat16* pOt   = (__hip_bfloat16*)(w2 + 393216 + 19668992);
  float* pML            = (float*)(w2 + 393216 + 19668992 + 25690112);

  dim3 tb(256);
  dim3 tg(98, 8, 4);
  transpose_tok_kernel<<<tg, tb, 0, stream>>>(feat0, q0);
  transpose_tok_kernel<<<tg, tb, 0, stream>>>(feat1, f1);
  transpose_tok_kernel<<<tg, tb, 0, stream>>>(feat2, f2);
  transpose_tok_kernel<<<tg, tb, 0, stream>>>(feat3, f3);
  cvt_bf16_kernel<<<dim3((C_ * C_ + 255) / 256), tb, 0, stream>>>(Wv, Wv_bf, C_ * C_);
  cvt_bf16_kernel<<<dim3((C_ * 2 * C_ + 255) / 256), tb, 0, stream>>>(Wl, Wl_bf, C_ * 2 * C_);
  cvt_mask_kernel<<<dim3((N_ * N_ / 8 + 255) / 256), tb, 0, stream>>>(mask, maskb, N_ * N_ / 8);

  // slot 0: feat0 passthrough
  for (int b = 0; b < B_; ++b)
    hipMemcpyAsync(out + (size_t)b * 4 * C_ * N_, feat0 + (size_t)b * C_ * N_,
                   (size_t)C_ * N_ * sizeof(float), hipMemcpyDeviceToDevice, stream);

  const __hip_bfloat16* fs[3] = {f1, f2, f3};
  __hip_bfloat16* refs[2] = {refA, refB};
  const __hip_bfloat16* q = q0;
  for (int s = 0; s < 3; ++s) {
    const __hip_bfloat16* f = fs[s];
    v_linear_kernel<<<dim3(49, 4, 4), tb, 0, stream>>>(f, Wv_bf, bv, vT);
    attn_kernel<<<dim3(400), dim3(256), 0, stream>>>(q, f, vT, maskb, pOt, pML);
    combine_kernel<<<dim3(196, 4), tb, 0, stream>>>(pOt, pML, f, refs[s & 1]);
    out_linear_kernel<<<dim3(49, 4, 4), tb, 0, stream>>>(refs[s & 1], f, Wl_bf, bl,
                                                         out + (size_t)(s + 1) * C_ * N_);
    q = refs[s & 1];
  }
}

// Round 5
// 502.785 us; speedup vs baseline: 1.5132x; 1.5132x over previous
//
#include <hip/hip_runtime.h>
#include <hip/hip_bf16.h>

// Problem constants
#define B_   4
#define C_   256
#define N_   3136
#define QT_  196     // N/16 q-tiles per batch
#define NKV_ 98      // N/32 kv tiles
#define CH_  5       // KV chunks (grid balance: 4*5*25=500 blocks ~= 2/CU)

typedef __attribute__((ext_vector_type(8))) short bf16x8;
typedef __attribute__((ext_vector_type(4))) float f32x4;

#define LOG2E  1.4426950408889634f
#define SCALE2 (LOG2E / 16.0f)     // (1/sqrt(C)) * log2(e)

__device__ __forceinline__ unsigned short bfbits(float f) {
  __hip_bfloat16 h = __float2bfloat16(f);
  return *(unsigned short*)&h;
}

// ---- async global->LDS 16B helper (dest must be linear: base + lane*16) ----
__device__ __forceinline__ void gld16(const void* g, void* l) {
  __builtin_amdgcn_global_load_lds(
      (const __attribute__((address_space(1))) unsigned int*)g,
      (__attribute__((address_space(3))) unsigned int*)l, 16, 0, 0);
}

// ---- all 4 feats: [b][c][n] f32 -> [b][n][c] bf16; feat0 also copied to out slot 0 ----
__global__ __launch_bounds__(256) void transpose4_kernel(
    const float* __restrict__ f0, const float* __restrict__ f1,
    const float* __restrict__ f2, const float* __restrict__ f3,
    __hip_bfloat16* __restrict__ d0, __hip_bfloat16* __restrict__ d1,
    __hip_bfloat16* __restrict__ d2, __hip_bfloat16* __restrict__ d3,
    float* __restrict__ out) {
  __shared__ float tile[32][33];
  const int z  = blockIdx.z;
  const int fi = z >> 2;
  const int b  = z & 3;
  const float* src = (fi == 0) ? f0 : (fi == 1) ? f1 : (fi == 2) ? f2 : f3;
  __hip_bfloat16* dst = (fi == 0) ? d0 : (fi == 1) ? d1 : (fi == 2) ? d2 : d3;
  const int n0 = blockIdx.x * 32;
  const int c0 = blockIdx.y * 32;
  const int tx = threadIdx.x & 31;
  const int ty = threadIdx.x >> 5;     // 0..7
  const float* s = src + (size_t)b * C_ * N_;
  float* ob = out + (size_t)b * 4 * C_ * N_;
#pragma unroll
  for (int i = 0; i < 4; ++i) {
    int c = c0 + ty + i * 8;
    float v = s[(size_t)c * N_ + n0 + tx];
    tile[ty + i * 8][tx] = v;
    if (fi == 0) ob[(size_t)c * N_ + n0 + tx] = v;   // slot-0 passthrough
  }
  __syncthreads();
  __hip_bfloat16* d = dst + (size_t)b * N_ * C_;
#pragma unroll
  for (int i = 0; i < 4; ++i) {
    int n = n0 + ty + i * 8;
    d[(size_t)n * C_ + c0 + tx] = __float2bfloat16(tile[tx][ty + i * 8]);
  }
}

// ---- fused f32->bf16 converts: Wv (8192 grp), Wl (16384 grp), mask (1229312 grp) ----
__global__ __launch_bounds__(256) void cvt_all_kernel(
    const float* __restrict__ Wv, const float* __restrict__ Wl,
    const float* __restrict__ mask,
    __hip_bfloat16* __restrict__ Wvb, __hip_bfloat16* __restrict__ Wlb,
    __hip_bfloat16* __restrict__ maskb) {
  int i = blockIdx.x * 256 + threadIdx.x;
  const float* src; __hip_bfloat16* dst; int off;
  if (i < 8192)        { src = Wv;   dst = Wvb;   off = i; }
  else if (i < 24576)  { src = Wl;   dst = Wlb;   off = i - 8192; }
  else if (i < 24576 + 1229312) { src = mask; dst = maskb; off = i - 24576; }
  else return;
  const float4* s4 = (const float4*)src;
  float4 a = s4[2 * off], b = s4[2 * off + 1];
  union { unsigned short u[8]; bf16x8 v; } p;
  p.u[0] = bfbits(a.x); p.u[1] = bfbits(a.y); p.u[2] = bfbits(a.z); p.u[3] = bfbits(a.w);
  p.u[4] = bfbits(b.x); p.u[5] = bfbits(b.y); p.u[6] = bfbits(b.z); p.u[7] = bfbits(b.w);
  *(bf16x8*)(dst + 8 * off) = p.v;
}

// ---- vT[b][c][n] = sum_k Wv[c][k] * f[b][n][k] + bv[c]   (written transposed) ----
__global__ __launch_bounds__(256) void v_linear_kernel(
    const __hip_bfloat16* __restrict__ fb,   // [B][N][C]
    const __hip_bfloat16* __restrict__ Wv,   // [C][C] bf16
    const float* __restrict__ bv,
    __hip_bfloat16* __restrict__ vT)         // [B][C][N]
{
  const int b    = blockIdx.z;
  const int cblk = blockIdx.y;
  const int nblk = blockIdx.x;
  const int wave = threadIdx.x >> 6;
  const int lane = threadIdx.x & 63;
  const int qt = lane & 15, g = lane >> 4;
  const int c0 = cblk * 64 + wave * 16;
  const int n0 = nblk * 64;
  const __hip_bfloat16* fbb = fb + (size_t)b * N_ * C_;
  f32x4 acc[4];
#pragma unroll
  for (int j = 0; j < 4; ++j) acc[j] = (f32x4){0.f, 0.f, 0.f, 0.f};
#pragma unroll
  for (int kk = 0; kk < 8; ++kk) {
    int ko = kk * 32 + g * 8;
    bf16x8 a = *(const bf16x8*)(Wv + (size_t)(c0 + qt) * C_ + ko);
#pragma unroll
    for (int j = 0; j < 4; ++j) {
      bf16x8 bb = *(const bf16x8*)(fbb + (size_t)(n0 + j * 16 + qt) * C_ + ko);
      acc[j] = __builtin_amdgcn_mfma_f32_16x16x32_bf16(a, bb, acc[j], 0, 0, 0);
    }
  }
  __hip_bfloat16* out = vT + (size_t)b * C_ * N_;
#pragma unroll
  for (int j = 0; j < 4; ++j)
#pragma unroll
    for (int r = 0; r < 4; ++r) {
      int c = c0 + 4 * g + r;
      int n = n0 + j * 16 + qt;
      out[(size_t)c * N_ + n] = __float2bfloat16(acc[j][r] + bv[c]);
    }
}

// ---- flash attention: 8 waves, dbuf K/V, counted vmcnt, defer-max softmax ----
__global__ __launch_bounds__(512) void attn_kernel(
    const __hip_bfloat16* __restrict__ qb,   // [B][N][C]
    const __hip_bfloat16* __restrict__ kb,   // [B][N][C]
    const __hip_bfloat16* __restrict__ vT,   // [B][C][N]
    const __hip_bfloat16* __restrict__ mb,   // [N][N] bf16
    __hip_bfloat16* __restrict__ pOt,        // [B][196][CH][col*16+row] bf16
    float* __restrict__ pML)                 // [B][196][CH][2][16]
{
  __shared__ __hip_bfloat16 Kl[2][32 * 256];   // 2 x 16KB
  __shared__ __hip_bfloat16 Vl[2][256 * 32];   // 2 x 16KB
  __shared__ __hip_bfloat16 Pl[8][512];        // 8KB

  const int bid   = blockIdx.x;       // 0..499
  const int grp   = bid % 20;         // (b,chunk)
  const int qblk  = bid / 20;         // 0..24
  const int b     = grp / CH_;
  const int chunk = grp % CH_;
  const int wave  = threadIdx.x >> 6;
  const int lane  = threadIdx.x & 63;
  const int qt = lane & 15, g = lane >> 4;
  const int qtile = qblk * 8 + wave;
  const bool valid = qtile < QT_;
  const int q0 = (valid ? qtile : QT_ - 1) * 16;
  const int t0 = (chunk * NKV_) / CH_;
  const int t1 = ((chunk + 1) * NKV_) / CH_;
  const int nt = t1 - t0;

  const __hip_bfloat16* qbb = qb + (size_t)b * N_ * C_;
  const __hip_bfloat16* kbb = kb + (size_t)b * N_ * C_;
  const __hip_bfloat16* vbb = vT + (size_t)b * C_ * N_;

  bf16x8 qa[8];
#pragma unroll
  for (int kk = 0; kk < 8; ++kk)
    qa[kk] = *(const bf16x8*)(qbb + (size_t)(q0 + qt) * C_ + kk * 32 + g * 8);

  f32x4 o[16];
#pragma unroll
  for (int i = 0; i < 16; ++i) o[i] = (f32x4){0.f, 0.f, 0.f, 0.f};
  float mrow[4] = {-1e30f, -1e30f, -1e30f, -1e30f};
  float lrow[4] = {0.f, 0.f, 0.f, 0.f};

  char* Pw = (char*)&Pl[wave][0];
  const int tid = threadIdx.x;

  // stage K/V tile t into buffer buf: 4 gld16 per thread (512 threads)
  auto STAGE = [&](int buf, int t) {
    const int k0 = t * 32;
#pragma unroll
    for (int i = 0; i < 2; ++i) {     // K: 32 rows x 512B; slot s holds key perm(s)
      int off  = (tid + i * 512) * 16;
      int slot = off >> 9;
      int key  = (slot < 16) ? (2 * slot) : (2 * slot - 31);
      int cb   = (off & 511) ^ ((slot & 7) << 4);
      gld16((const char*)(kbb + (size_t)(k0 + key) * C_) + cb, (char*)&Kl[buf][0] + off);
    }
#pragma unroll
    for (int i = 0; i < 2; ++i) {     // V^T: 256 rows x 64B, natural key order
      int off = (tid + i * 512) * 16;
      int row = off >> 6;
      int cb  = (off & 63) ^ (((row >> 1) & 3) << 4);
      gld16((const char*)(vbb + (size_t)row * N_ + k0) + cb, (char*)&Vl[buf][0] + off);
    }
  };
  // prefetch mask for tile t into 4 regs (2 bf16 each)
  auto MLOAD = [&](int t, unsigned int (&mm)[4]) {
    const int k0 = t * 32;
#pragma unroll
    for (int r = 0; r < 4; ++r)
      mm[r] = *(const unsigned int*)(mb + (size_t)(q0 + 4 * g + r) * N_ + k0 + 2 * qt);
  };

  auto BODY = [&](int tti, int buf, unsigned int (&mcur)[4], unsigned int (&mnext)[4]) {
    if (tti + 1 < nt) {
      MLOAD(t0 + tti + 1, mnext);
      STAGE(buf ^ 1, t0 + tti + 1);
      asm volatile("s_waitcnt vmcnt(8)" ::: "memory");  // cur stage done; next 8 in flight
    } else {
      asm volatile("s_waitcnt vmcnt(0)" ::: "memory");
    }
    __builtin_amdgcn_s_barrier();

    if (valid) {
      // ---- S = Q @ K^T : col qt <-> key 2qt (s0), 2qt+1 (s1) ----
      f32x4 s0 = (f32x4){0.f,0.f,0.f,0.f}, s1 = (f32x4){0.f,0.f,0.f,0.f};
      const char* Kb = (const char*)&Kl[buf][0];
      __builtin_amdgcn_s_setprio(1);
#pragma unroll
      for (int kk = 0; kk < 8; ++kk) {
        int cb = (kk * 64 + g * 16) ^ ((qt & 7) << 4);
        bf16x8 kf0 = *(const bf16x8*)(Kb + qt * 512 + cb);
        s0 = __builtin_amdgcn_mfma_f32_16x16x32_bf16(qa[kk], kf0, s0, 0, 0, 0);
        bf16x8 kf1 = *(const bf16x8*)(Kb + (16 + qt) * 512 + cb);
        s1 = __builtin_amdgcn_mfma_f32_16x16x32_bf16(qa[kk], kf1, s1, 0, 0, 0);
      }
      __builtin_amdgcn_s_setprio(0);

      // ---- defer-max online softmax (exp2 domain) ----
      float v0[4], v1[4];
      unsigned long long bal = 0ull;
#pragma unroll
      for (int r = 0; r < 4; ++r) {
        float mf0 = __uint_as_float(mcur[r] << 16);
        float mf1 = __uint_as_float(mcur[r] & 0xffff0000u);
        v0[r] = fmaf(mf0, LOG2E, s0[r] * SCALE2);
        v1[r] = fmaf(mf1, LOG2E, s1[r] * SCALE2);
        float vm = fmaxf(v0[r], v1[r]);
        bal |= __ballot(vm > mrow[r] + 8.f);
      }
      if (bal) {                   // rare: row max grew -> rescale
        float frv[4];
#pragma unroll
        for (int r = 0; r < 4; ++r) {
          float mx = fmaxf(v0[r], v1[r]);
#pragma unroll
          for (int d = 1; d < 16; d <<= 1) mx = fmaxf(mx, __shfl_xor(mx, d));
          float mn = fmaxf(mrow[r], mx);
          frv[r] = exp2f(mrow[r] - mn);
          mrow[r] = mn;
          lrow[r] *= frv[r];
        }
#pragma unroll
        for (int ct = 0; ct < 16; ++ct) {
          o[ct][0] *= frv[0]; o[ct][1] *= frv[1];
          o[ct][2] *= frv[2]; o[ct][3] *= frv[3];
        }
      }
#pragma unroll
      for (int r = 0; r < 4; ++r) {
        float p0 = exp2f(v0[r] - mrow[r]);
        float p1 = exp2f(v1[r] - mrow[r]);
        lrow[r] += p0 + p1;
        unsigned int pk = (unsigned int)bfbits(p0) | ((unsigned int)bfbits(p1) << 16);
        int r4 = 4 * g + r;
        *(unsigned int*)(Pw + r4 * 64 + ((qt * 4) ^ (((r4 >> 1) & 3) << 4))) = pk;
      }
      bf16x8 pa = *(const bf16x8*)(Pw + qt * 64 + ((g * 16) ^ (((qt >> 1) & 3) << 4)));

      // ---- O += P @ V ----
      const char* Vb = (const char*)&Vl[buf][0];
      __builtin_amdgcn_s_setprio(1);
#pragma unroll
      for (int ct = 0; ct < 16; ++ct) {
        int row = ct * 16 + qt;
        int cb  = (g * 16) ^ (((row >> 1) & 3) << 4);
        bf16x8 vf = *(const bf16x8*)(Vb + row * 64 + cb);
        o[ct] = __builtin_amdgcn_mfma_f32_16x16x32_bf16(pa, vf, o[ct], 0, 0, 0);
      }
      __builtin_amdgcn_s_setprio(0);
    }
    __builtin_amdgcn_s_barrier();   // all waves done with buf before it is restaged
  };

  unsigned int mmA[4], mmB[4];
  STAGE(0, t0);
  MLOAD(t0, mmA);
  for (int tt = 0; tt < nt; tt += 2) {
    BODY(tt, 0, mmA, mmB);
    if (tt + 1 < nt) BODY(tt + 1, 1, mmB, mmA);
  }

  if (valid) {
    // final cross-lane reduce of deferred l partials
#pragma unroll
    for (int r = 0; r < 4; ++r) {
      float s = lrow[r];
#pragma unroll
      for (int d = 1; d < 16; d <<= 1) s += __shfl_xor(s, d);
      lrow[r] = s;
    }
    // pOt: per (b,qtile,chunk): 256 cols x 16 rows bf16, col-major rows-contig
    __hip_bfloat16* po = pOt + (((size_t)b * QT_ + qtile) * CH_ + chunk) * 4096;
#pragma unroll
    for (int ct = 0; ct < 16; ++ct) {
      unsigned int lo = (unsigned int)bfbits(o[ct][0]) | ((unsigned int)bfbits(o[ct][1]) << 16);
      unsigned int hi = (unsigned int)bfbits(o[ct][2]) | ((unsigned int)bfbits(o[ct][3]) << 16);
      uint2 pk = make_uint2(lo, hi);
      *(uint2*)((char*)po + (ct * 16 + qt) * 32 + 8 * g) = pk;   // 8B coalesced
    }
    if (qt == 0) {
      float* pml = pML + (((size_t)b * QT_ + qtile) * CH_ + chunk) * 32;
#pragma unroll
      for (int r = 0; r < 4; ++r) {
        pml[4 * g + r]      = mrow[r];
        pml[16 + 4 * g + r] = lrow[r];
      }
    }
  }
}

// ---- combine CH KV-chunk partials; refined = O/l + f  -> bf16 [b][n][c] ----
// thread c (0..255) owns channel c; reads 16 contiguous rows per chunk
__global__ __launch_bounds__(256) void combine_kernel(
    const __hip_bfloat16* __restrict__ pOt, const float* __restrict__ pML,
    const __hip_bfloat16* __restrict__ fb,
    __hip_bfloat16* __restrict__ ref)
{
  __shared__ float sml[CH_ * 32];
  const int b = blockIdx.y;
  const int qtile = blockIdx.x;
  const int c = threadIdx.x;
  const float* pml = pML + ((size_t)b * QT_ + qtile) * CH_ * 32;
  if (c < CH_ * 32) sml[c] = pml[c];
  __syncthreads();

  float wgt[CH_][16];
#pragma unroll
  for (int row = 0; row < 16; ++row) {
    float M = -1e30f;
#pragma unroll
    for (int ch = 0; ch < CH_; ++ch) M = fmaxf(M, sml[ch * 32 + row]);
    float L = 0.f;
#pragma unroll
    for (int ch = 0; ch < CH_; ++ch) {
      float wv = exp2f(sml[ch * 32 + row] - M);
      wgt[ch][row] = wv;
      L += wv * sml[ch * 32 + 16 + row];
    }
    float iL = 1.f / L;
#pragma unroll
    for (int ch = 0; ch < CH_; ++ch) wgt[ch][row] *= iL;
  }

  float acc[16];
#pragma unroll
  for (int row = 0; row < 16; ++row) acc[row] = 0.f;
#pragma unroll
  for (int ch = 0; ch < CH_; ++ch) {
    const __hip_bfloat16* p = pOt + (((size_t)b * QT_ + qtile) * CH_ + ch) * 4096 + c * 16;
    bf16x8 x0 = *(const bf16x8*)p;
    bf16x8 x1 = *(const bf16x8*)(p + 8);
#pragma unroll
    for (int row = 0; row < 8; ++row) {
      acc[row]     += wgt[ch][row]     * __uint_as_float((unsigned int)(unsigned short)x0[row] << 16);
      acc[row + 8] += wgt[ch][row + 8] * __uint_as_float((unsigned int)(unsigned short)x1[row] << 16);
    }
  }

  const __hip_bfloat16* f = fb + ((size_t)b * N_ + qtile * 16) * C_ + c;
  __hip_bfloat16* rf = ref + ((size_t)b * N_ + qtile * 16) * C_ + c;
#pragma unroll
  for (int row = 0; row < 16; ++row)
    rf[row * C_] = __float2bfloat16(acc[row] + __bfloat162float(f[row * C_]));
}

// ---- out[c][n] = Wl[:, :256] @ refined^T + Wl[:, 256:] @ f^T + bl ----
__global__ __launch_bounds__(256) void out_linear_kernel(
    const __hip_bfloat16* __restrict__ refb,
    const __hip_bfloat16* __restrict__ fb,
    const __hip_bfloat16* __restrict__ Wl,   // [256][512]
    const float* __restrict__ bl,
    float* __restrict__ out)
{
  const int b    = blockIdx.z;
  const int cblk = blockIdx.y;
  const int nblk = blockIdx.x;
  const int wave = threadIdx.x >> 6;
  const int lane = threadIdx.x & 63;
  const int qt = lane & 15, g = lane >> 4;
  const int c0 = cblk * 64 + wave * 16;
  const int n0 = nblk * 64;
  const __hip_bfloat16* rb  = refb + (size_t)b * N_ * C_;
  const __hip_bfloat16* fbb = fb  + (size_t)b * N_ * C_;
  f32x4 acc[4];
#pragma unroll
  for (int j = 0; j < 4; ++j) acc[j] = (f32x4){0.f, 0.f, 0.f, 0.f};
#pragma unroll
  for (int kk = 0; kk < 8; ++kk) {
    int ko = kk * 32 + g * 8;
    bf16x8 a = *(const bf16x8*)(Wl + (size_t)(c0 + qt) * 512 + ko);
#pragma unroll
    for (int j = 0; j < 4; ++j) {
      bf16x8 bb = *(const bf16x8*)(rb + (size_t)(n0 + j * 16 + qt) * C_ + ko);
      acc[j] = __builtin_amdgcn_mfma_f32_16x16x32_bf16(a, bb, acc[j], 0, 0, 0);
    }
  }
#pragma unroll
  for (int kk = 0; kk < 8; ++kk) {
    int ko = kk * 32 + g * 8;
    bf16x8 a = *(const bf16x8*)(Wl + (size_t)(c0 + qt) * 512 + 256 + ko);
#pragma unroll
    for (int j = 0; j < 4; ++j) {
      bf16x8 bb = *(const bf16x8*)(fbb + (size_t)(n0 + j * 16 + qt) * C_ + ko);
      acc[j] = __builtin_amdgcn_mfma_f32_16x16x32_bf16(a, bb, acc[j], 0, 0, 0);
    }
  }
  float* ob = out + (size_t)b * 4 * C_ * N_;
#pragma unroll
  for (int j = 0; j < 4; ++j)
#pragma unroll
    for (int r = 0; r < 4; ++r) {
      int c = c0 + 4 * g + r;
      int n = n0 + j * 16 + qt;
      ob[(size_t)c * N_ + n] = acc[j][r] + bl[c];
    }
}

extern "C" void kernel_launch(void* const* d_in, const int* in_sizes, int n_in,
                              void* d_out, int out_size, void* d_ws, size_t ws_size,
                              hipStream_t stream) {
  (void)in_sizes; (void)n_in; (void)out_size; (void)ws_size;
  const float* feat0 = (const float*)d_in[0];
  const float* feat1 = (const float*)d_in[1];
  const float* feat2 = (const float*)d_in[2];
  const float* feat3 = (const float*)d_in[3];
  const float* mask  = (const float*)d_in[7];
  const float* Wv    = (const float*)d_in[8];
  const float* bv    = (const float*)d_in[9];
  const float* Wl    = (const float*)d_in[10];
  const float* bl    = (const float*)d_in[11];
  float* out = (float*)d_out;

  const size_t TOKB = (size_t)B_ * N_ * C_ * 2;  // 6,422,528
  char* w = (char*)d_ws;
  __hip_bfloat16* q0   = (__hip_bfloat16*)(w);
  __hip_bfloat16* f1   = (__hip_bfloat16*)(w + TOKB);
  __hip_bfloat16* f2   = (__hip_bfloat16*)(w + 2 * TOKB);
  __hip_bfloat16* f3   = (__hip_bfloat16*)(w + 3 * TOKB);
  __hip_bfloat16* vT   = (__hip_bfloat16*)(w + 4 * TOKB);
  __hip_bfloat16* refA = (__hip_bfloat16*)(w + 5 * TOKB);
  __hip_bfloat16* refB = (__hip_bfloat16*)(w + 6 * TOKB);
  char* w2 = w + 7 * TOKB;
  __hip_bfloat16* Wv_bf = (__hip_bfloat16*)(w2);                    // 131072 B
  __hip_bfloat16* Wl_bf = (__hip_bfloat16*)(w2 + 131072);           // 262144 B
  __hip_bfloat16* maskb = (__hip_bfloat16*)(w2 + 393216);           // 19668992 B
  __hip_bfloat16* pOt   = (__hip_bfloat16*)(w2 + 393216 + 19668992);           // B*QT*CH*4096*2
  float* pML            = (float*)(w2 + 393216 + 19668992 + (size_t)B_ * QT_ * CH_ * 4096 * 2);

  dim3 tb(256);
  transpose4_kernel<<<dim3(98, 8, 16), tb, 0, stream>>>(feat0, feat1, feat2, feat3,
                                                        q0, f1, f2, f3, out);
  cvt_all_kernel<<<dim3((24576 + 1229312 + 255) / 256), tb, 0, stream>>>(
      Wv, Wl, mask, Wv_bf, Wl_bf, maskb);

  const __hip_bfloat16* fs[3] = {f1, f2, f3};
  __hip_bfloat16* refs[2] = {refA, refB};
  const __hip_bfloat16* q = q0;
  for (int s = 0; s < 3; ++s) {
    const __hip_bfloat16* f = fs[s];
    v_linear_kernel<<<dim3(49, 4, 4), tb, 0, stream>>>(f, Wv_bf, bv, vT);
    attn_kernel<<<dim3(500), dim3(512), 0, stream>>>(q, f, vT, maskb, pOt, pML);
    combine_kernel<<<dim3(196, 4), tb, 0, stream>>>(pOt, pML, f, refs[s & 1]);
    out_linear_kernel<<<dim3(49, 4, 4), tb, 0, stream>>>(refs[s & 1], f, Wl_bf, bl,
                                                         out + (size_t)(s + 1) * C_ * N_);
    q = refs[s & 1];
  }
}